// Round 1
// baseline (15985.323 us; speedup 1.0000x reference)
//
#include <hip/hip_runtime.h>

namespace {

constexpr int kNP = 50000, kNT = 200000, kNA = 20000;
constexpr int kEPT = 1000000, kETP = 1000000, kEAT = 400000, kETA = 400000;
constexpr int DIN = 128, DH = 256, DO = 128;

// ---------------- weight prep ----------------

// in: [4][R][C] row-major; out: [4][C][R] (transposed per matrix), scaled per-matrix
__global__ __launch_bounds__(256) void prep_transpose4(
    const float* __restrict__ in, float* __restrict__ out, int R, int C,
    float s0, float s1, float s2, float s3) {
  int gid = blockIdx.x * 256 + threadIdx.x;
  int per = R * C;
  if (gid >= 4 * per) return;
  int e = gid / per;
  int rem = gid - e * per;
  int r = rem / C;
  int c = rem - r * C;
  float s = (e == 0) ? s0 : (e == 1) ? s1 : (e == 2) ? s2 : s3;
  out[(size_t)e * per + (size_t)c * R + r] = in[gid] * s;
}

// Combined residual+self weights, transposed:
// WcT[0][k][o] = Wres[1][o][k] + 0.5*(W2r[0][o][k] + W2r[2][o][k])   (track)
// WcT[1][k][o] = Wres[0][o][k] + W2r[1][o][k]                        (playlist)
// WcT[2][k][o] = Wres[2][o][k] + W2r[3][o][k]                        (artist)
// bc similarly from bres/b2.
__global__ __launch_bounds__(256) void prep_comb(
    const float* __restrict__ Wres, const float* __restrict__ W2r,
    const float* __restrict__ bres, const float* __restrict__ b2,
    float* __restrict__ WcT, float* __restrict__ bc) {
  int gid = blockIdx.x * 256 + threadIdx.x;
  const int per = DO * DH;  // 128*256
  if (gid < 3 * per) {
    int b = gid / per;
    int rem = gid - b * per;
    int k = rem / DO;
    int o = rem - k * DO;
    int resIdx = (b == 0) ? 1 : (b == 1) ? 0 : 2;
    float v = Wres[(size_t)resIdx * per + (size_t)o * DH + k];
    if (b == 0)
      v += 0.5f * (W2r[(size_t)0 * per + (size_t)o * DH + k] +
                   W2r[(size_t)2 * per + (size_t)o * DH + k]);
    else if (b == 1)
      v += W2r[(size_t)1 * per + (size_t)o * DH + k];
    else
      v += W2r[(size_t)3 * per + (size_t)o * DH + k];
    WcT[gid] = v;
  }
  if (gid < 3 * DO) {
    int b = gid / DO;
    int o = gid - b * DO;
    int resIdx = (b == 0) ? 1 : (b == 1) ? 0 : 2;
    float v = bres[resIdx * DO + o];
    if (b == 0)
      v += 0.5f * (b2[0 * DO + o] + b2[2 * DO + o]);
    else if (b == 1)
      v += b2[1 * DO + o];
    else
      v += b2[3 * DO + o];
    bc[gid] = v;
  }
}

// scaled copy of b1: entries 0 and 2 get *0.5 (track conv mean over 2 edge types)
__global__ __launch_bounds__(256) void prep_b1(const float* __restrict__ b1,
                                               float* __restrict__ b1s) {
  int gid = blockIdx.x * 256 + threadIdx.x;
  if (gid < 4 * DH) {
    int e = gid / DH;
    b1s[gid] = b1[gid] * ((e == 0 || e == 2) ? 0.5f : 1.0f);
  }
}

// ---------------- aggregation ----------------

__global__ __launch_bounds__(256) void count_kernel(const int* __restrict__ dst,
                                                    int E,
                                                    float* __restrict__ cnt) {
  int gid = blockIdx.x * 256 + threadIdx.x;
  if (gid < E) atomicAdd(&cnt[dst[gid]], 1.0f);
}

// Scatter-add X[src[e]] (optionally + Xadd[src[e]]) into agg[dst[e]], D4 float4s per row
__global__ __launch_bounds__(256) void scatter_kernel(
    const float* __restrict__ X, const float* __restrict__ Xadd,
    const int* __restrict__ src, const int* __restrict__ dst, int E, int D4,
    float* __restrict__ agg) {
  int gid = blockIdx.x * 256 + threadIdx.x;
  if (gid >= E * D4) return;
  int e = gid / D4;
  int c = gid - e * D4;
  int s = src[e];
  int d = dst[e];
  float4 v = reinterpret_cast<const float4*>(X)[(size_t)s * D4 + c];
  if (Xadd != nullptr) {
    float4 w = reinterpret_cast<const float4*>(Xadd)[(size_t)s * D4 + c];
    v.x += w.x; v.y += w.y; v.z += w.z; v.w += w.w;
  }
  float* outp = agg + ((size_t)d * D4 + c) * 4;
  atomicAdd(outp + 0, v.x);
  atomicAdd(outp + 1, v.y);
  atomicAdd(outp + 2, v.z);
  atomicAdd(outp + 3, v.w);
}

// ---------------- GEMM ----------------
// C[n][o] (= or +=) relu?( (A1[n]/max(cnt,1)) @ B1T + (A2[n](+A2b[n])) @ B2T + bias )
// B*T are [K][DOUT] row-major (already transposed+scaled on device).
template <int K, int DOUT, bool HAS_A2, bool HAS_A2B, bool HAS_CNT, bool ACC,
          bool RELU, bool HAS_BIAS>
__global__ __launch_bounds__(256) void gemm_kernel(
    const float* __restrict__ A1, const float* __restrict__ cnt,
    const float* __restrict__ A2, const float* __restrict__ A2b,
    const float* __restrict__ B1T, const float* __restrict__ B2T,
    const float* __restrict__ bias, float* __restrict__ C, int N) {
  constexpr int KC = 16;
  constexpr int ROWS = 64;
  constexpr int CT = DOUT / 4;    // threads covering cols (64 for 256, 32 for 128)
  constexpr int RG = 256 / CT;    // row groups (4 or 8)
  constexpr int RPT = ROWS / RG;  // rows per thread (16 or 8)

  __shared__ float A1s[KC][ROWS];
  __shared__ float A2s[HAS_A2 ? KC : 1][HAS_A2 ? ROWS : 1];
  __shared__ float B1s[KC][DOUT];
  __shared__ float B2s[HAS_A2 ? KC : 1][HAS_A2 ? DOUT : 1];

  const int tid = threadIdx.x;
  const int tc = tid % CT;
  const int tg = tid / CT;
  const int n0 = blockIdx.x * ROWS;

  float acc[RPT][4];
#pragma unroll
  for (int r = 0; r < RPT; ++r)
#pragma unroll
    for (int j = 0; j < 4; ++j) acc[r][j] = 0.f;

  for (int kc0 = 0; kc0 < K; kc0 += KC) {
    // load A tile, transposed to [k][row] (256 threads x 1 float4 = 64x16)
    {
      int row = tid >> 2;
      int k4 = tid & 3;
      int n = n0 + row;
      float4 v = make_float4(0.f, 0.f, 0.f, 0.f);
      float4 v2 = make_float4(0.f, 0.f, 0.f, 0.f);
      if (n < N) {
        v = reinterpret_cast<const float4*>(A1 + (size_t)n * K + kc0)[k4];
        if constexpr (HAS_CNT) {
          float inv = 1.0f / fmaxf(cnt[n], 1.0f);
          v.x *= inv; v.y *= inv; v.z *= inv; v.w *= inv;
        }
        if constexpr (HAS_A2) {
          v2 = reinterpret_cast<const float4*>(A2 + (size_t)n * K + kc0)[k4];
          if constexpr (HAS_A2B) {
            float4 vb =
                reinterpret_cast<const float4*>(A2b + (size_t)n * K + kc0)[k4];
            v2.x += vb.x; v2.y += vb.y; v2.z += vb.z; v2.w += vb.w;
          }
        }
      }
      A1s[k4 * 4 + 0][row] = v.x;
      A1s[k4 * 4 + 1][row] = v.y;
      A1s[k4 * 4 + 2][row] = v.z;
      A1s[k4 * 4 + 3][row] = v.w;
      if constexpr (HAS_A2) {
        A2s[k4 * 4 + 0][row] = v2.x;
        A2s[k4 * 4 + 1][row] = v2.y;
        A2s[k4 * 4 + 2][row] = v2.z;
        A2s[k4 * 4 + 3][row] = v2.w;
      }
    }
    // load B tile [KC][DOUT]
    {
      constexpr int TOT4 = KC * DOUT / 4;
#pragma unroll
      for (int i = tid; i < TOT4; i += 256) {
        int kk = i / (DOUT / 4);
        int c4 = i - kk * (DOUT / 4);
        reinterpret_cast<float4*>(&B1s[kk][0])[c4] =
            reinterpret_cast<const float4*>(B1T + (size_t)(kc0 + kk) * DOUT)[c4];
        if constexpr (HAS_A2) {
          reinterpret_cast<float4*>(&B2s[kk][0])[c4] =
              reinterpret_cast<const float4*>(B2T +
                                              (size_t)(kc0 + kk) * DOUT)[c4];
        }
      }
    }
    __syncthreads();

#pragma unroll
    for (int k = 0; k < KC; ++k) {
      float4 b1q = reinterpret_cast<const float4*>(&B1s[k][0])[tc];
      float4 b2q;
      if constexpr (HAS_A2)
        b2q = reinterpret_cast<const float4*>(&B2s[k][0])[tc];
#pragma unroll
      for (int rq = 0; rq < RPT / 4; ++rq) {
        float4 a1q =
            *reinterpret_cast<const float4*>(&A1s[k][tg * RPT + rq * 4]);
        float4 a2q;
        if constexpr (HAS_A2)
          a2q = *reinterpret_cast<const float4*>(&A2s[k][tg * RPT + rq * 4]);
#pragma unroll
        for (int i = 0; i < 4; ++i) {
          float a1 = (i == 0) ? a1q.x : (i == 1) ? a1q.y : (i == 2) ? a1q.z : a1q.w;
          int r = rq * 4 + i;
          acc[r][0] += a1 * b1q.x;
          acc[r][1] += a1 * b1q.y;
          acc[r][2] += a1 * b1q.z;
          acc[r][3] += a1 * b1q.w;
          if constexpr (HAS_A2) {
            float a2 =
                (i == 0) ? a2q.x : (i == 1) ? a2q.y : (i == 2) ? a2q.z : a2q.w;
            acc[r][0] += a2 * b2q.x;
            acc[r][1] += a2 * b2q.y;
            acc[r][2] += a2 * b2q.z;
            acc[r][3] += a2 * b2q.w;
          }
        }
      }
    }
    __syncthreads();
  }

  float4 bq = make_float4(0.f, 0.f, 0.f, 0.f);
  if constexpr (HAS_BIAS) bq = reinterpret_cast<const float4*>(bias)[tc];
#pragma unroll
  for (int r = 0; r < RPT; ++r) {
    int n = n0 + tg * RPT + r;
    if (n < N) {
      float4 v = make_float4(acc[r][0], acc[r][1], acc[r][2], acc[r][3]);
      if constexpr (HAS_BIAS) {
        v.x += bq.x; v.y += bq.y; v.z += bq.z; v.w += bq.w;
      }
      float* cp = C + (size_t)n * DOUT + tc * 4;
      if constexpr (ACC) {
        float4 c0 = *reinterpret_cast<const float4*>(cp);
        v.x += c0.x; v.y += c0.y; v.z += c0.z; v.w += c0.w;
      }
      if constexpr (RELU) {
        v.x = fmaxf(v.x, 0.f); v.y = fmaxf(v.y, 0.f);
        v.z = fmaxf(v.z, 0.f); v.w = fmaxf(v.w, 0.f);
      }
      *reinterpret_cast<float4*>(cp) = v;
    }
  }
}

}  // namespace

extern "C" void kernel_launch(void* const* d_in, const int* in_sizes, int n_in,
                              void* d_out, int out_size, void* d_ws,
                              size_t ws_size, hipStream_t stream) {
  const float* x_p   = (const float*)d_in[0];
  const float* x_t   = (const float*)d_in[1];
  const float* x_a   = (const float*)d_in[2];
  const float* emb_p = (const float*)d_in[3];
  const float* emb_a = (const float*)d_in[4];
  const float* W1l   = (const float*)d_in[5];
  const float* b1    = (const float*)d_in[6];
  const float* W1r   = (const float*)d_in[7];
  const float* W2l   = (const float*)d_in[8];
  const float* b2    = (const float*)d_in[9];
  const float* W2r   = (const float*)d_in[10];
  const float* Wres  = (const float*)d_in[11];
  const float* bres  = (const float*)d_in[12];
  const int* e_pt = (const int*)d_in[13];
  const int* e_tp = (const int*)d_in[14];
  const int* e_at = (const int*)d_in[15];
  const int* e_ta = (const int*)d_in[16];

  float* out = (float*)d_out;
  float* p_out = out;
  float* t_out = out + (size_t)kNP * DO;
  float* a_out = out + (size_t)(kNP + kNT) * DO;

  float* ws = (float*)d_ws;
  size_t off = 0;
  auto alloc = [&](size_t nf) {
    float* p = ws + off;
    off += nf;
    return p;
  };
  float* t1 = alloc((size_t)kNT * DH);
  float* p1 = alloc((size_t)kNP * DH);
  float* a1 = alloc((size_t)kNA * DH);
  float* agg = alloc((size_t)kNT * DH);
  float* cnt_pt = alloc(kNT);
  float* cnt_at = alloc(kNT);
  float* cnt_tp = alloc(kNP);
  float* cnt_ta = alloc(kNA);
  float* W1lT = alloc(4 * DIN * DH);
  float* W1rT = alloc(4 * DIN * DH);
  float* W2lT = alloc(4 * DH * DO);
  float* WcT = alloc(3 * DH * DO);
  float* bc = alloc(3 * DO);
  float* b1s = alloc(4 * DH);
  (void)ws_size; (void)in_sizes; (void)n_in; (void)out_size;

  const int perW1 = DIN * DH;  // 32768
  const int perW2 = DH * DO;   // 32768

  // ---- weight prep ----
  prep_transpose4<<<(4 * perW1 + 255) / 256, 256, 0, stream>>>(
      W1l, W1lT, DH, DIN, 0.5f, 1.f, 0.5f, 1.f);
  prep_transpose4<<<(4 * perW1 + 255) / 256, 256, 0, stream>>>(
      W1r, W1rT, DH, DIN, 0.5f, 1.f, 0.5f, 1.f);
  prep_transpose4<<<(4 * perW2 + 255) / 256, 256, 0, stream>>>(
      W2l, W2lT, DO, DH, 0.5f, 1.f, 0.5f, 1.f);
  prep_comb<<<(3 * perW2 + 255) / 256, 256, 0, stream>>>(Wres, W2r, bres, b2,
                                                         WcT, bc);
  prep_b1<<<4, 256, 0, stream>>>(b1, b1s);

  // ---- degree counts (shared by both conv layers) ----
  hipMemsetAsync(cnt_pt, 0, (size_t)(kNT + kNT + kNP + kNA) * 4, stream);
  count_kernel<<<(kEPT + 255) / 256, 256, 0, stream>>>(e_pt + kEPT, kEPT, cnt_pt);
  count_kernel<<<(kEAT + 255) / 256, 256, 0, stream>>>(e_at + kEAT, kEAT, cnt_at);
  count_kernel<<<(kETP + 255) / 256, 256, 0, stream>>>(e_tp + kETP, kETP, cnt_tp);
  count_kernel<<<(kETA + 255) / 256, 256, 0, stream>>>(e_ta + kETA, kETA, cnt_ta);

  const int D4in = DIN / 4, D4h = DH / 4;

  // ================= conv1 =================
  // track <- playlist (edge_pt), then track <- artist (edge_at), relu
  hipMemsetAsync(agg, 0, (size_t)kNT * DIN * 4, stream);
  scatter_kernel<<<(kEPT * D4in + 255) / 256, 256, 0, stream>>>(
      x_p, emb_p, e_pt, e_pt + kEPT, kEPT, D4in, agg);
  gemm_kernel<DIN, DH, true, false, true, false, false, true>
      <<<(kNT + 63) / 64, 256, 0, stream>>>(agg, cnt_pt, x_t, nullptr, W1lT,
                                            W1rT, b1s, t1, kNT);

  hipMemsetAsync(agg, 0, (size_t)kNT * DIN * 4, stream);
  scatter_kernel<<<(kEAT * D4in + 255) / 256, 256, 0, stream>>>(
      x_a, emb_a, e_at, e_at + kEAT, kEAT, D4in, agg);
  gemm_kernel<DIN, DH, true, false, true, true, true, true>
      <<<(kNT + 63) / 64, 256, 0, stream>>>(agg, cnt_at, x_t, nullptr,
                                            W1lT + 2 * perW1, W1rT + 2 * perW1,
                                            b1s + 2 * DH, t1, kNT);

  // playlist <- track (edge_tp), relu
  hipMemsetAsync(agg, 0, (size_t)kNP * DIN * 4, stream);
  scatter_kernel<<<(kETP * D4in + 255) / 256, 256, 0, stream>>>(
      x_t, nullptr, e_tp, e_tp + kETP, kETP, D4in, agg);
  gemm_kernel<DIN, DH, true, true, true, false, true, true>
      <<<(kNP + 63) / 64, 256, 0, stream>>>(agg, cnt_tp, x_p, emb_p,
                                            W1lT + 1 * perW1, W1rT + 1 * perW1,
                                            b1s + 1 * DH, p1, kNP);

  // artist <- track (edge_ta), relu
  hipMemsetAsync(agg, 0, (size_t)kNA * DIN * 4, stream);
  scatter_kernel<<<(kETA * D4in + 255) / 256, 256, 0, stream>>>(
      x_t, nullptr, e_ta, e_ta + kETA, kETA, D4in, agg);
  gemm_kernel<DIN, DH, true, true, true, false, true, true>
      <<<(kNA + 63) / 64, 256, 0, stream>>>(agg, cnt_ta, x_a, emb_a,
                                            W1lT + 3 * perW1, W1rT + 3 * perW1,
                                            b1s + 3 * DH, a1, kNA);

  // ================= conv2 (+ fused residual/self/bias via WcT/bc) =========
  // t_out = agg_pt/cnt @ (0.5*W2l0)T + t1 @ WcT[0] + bc[0]   ... then += at term
  hipMemsetAsync(agg, 0, (size_t)kNT * DH * 4, stream);
  scatter_kernel<<<(kEPT * D4h + 255) / 256, 256, 0, stream>>>(
      p1, nullptr, e_pt, e_pt + kEPT, kEPT, D4h, agg);
  gemm_kernel<DH, DO, true, false, true, false, false, true>
      <<<(kNT + 63) / 64, 256, 0, stream>>>(agg, cnt_pt, t1, nullptr, W2lT,
                                            WcT, bc, t_out, kNT);

  hipMemsetAsync(agg, 0, (size_t)kNT * DH * 4, stream);
  scatter_kernel<<<(kEAT * D4h + 255) / 256, 256, 0, stream>>>(
      a1, nullptr, e_at, e_at + kEAT, kEAT, D4h, agg);
  gemm_kernel<DH, DO, false, false, true, true, false, false>
      <<<(kNT + 63) / 64, 256, 0, stream>>>(agg, cnt_at, nullptr, nullptr,
                                            W2lT + 2 * perW2, nullptr, nullptr,
                                            t_out, kNT);

  // p_out
  hipMemsetAsync(agg, 0, (size_t)kNP * DH * 4, stream);
  scatter_kernel<<<(kETP * D4h + 255) / 256, 256, 0, stream>>>(
      t1, nullptr, e_tp, e_tp + kETP, kETP, D4h, agg);
  gemm_kernel<DH, DO, true, false, true, false, false, true>
      <<<(kNP + 63) / 64, 256, 0, stream>>>(agg, cnt_tp, p1, nullptr,
                                            W2lT + 1 * perW2, WcT + 1 * perW2,
                                            bc + DO, p_out, kNP);

  // a_out
  hipMemsetAsync(agg, 0, (size_t)kNA * DH * 4, stream);
  scatter_kernel<<<(kETA * D4h + 255) / 256, 256, 0, stream>>>(
      t1, nullptr, e_ta, e_ta + kETA, kETA, D4h, agg);
  gemm_kernel<DH, DO, true, false, true, false, false, true>
      <<<(kNA + 63) / 64, 256, 0, stream>>>(agg, cnt_ta, a1, nullptr,
                                            W2lT + 3 * perW2, WcT + 2 * perW2,
                                            bc + 2 * DO, a_out, kNA);
}

// Round 3
// 2265.650 us; speedup vs baseline: 7.0555x; 7.0555x over previous
//
#include <hip/hip_runtime.h>

namespace {

constexpr int kNP = 50000, kNT = 200000, kNA = 20000;
constexpr int kEPT = 1000000, kETP = 1000000, kEAT = 400000, kETA = 400000;
constexpr int DIN = 128, DH = 256, DO = 128;

// ---------------- weight prep ----------------

// in: [4][R][C] row-major; out: [4][C][R] (transposed per matrix), scaled per-matrix
__global__ __launch_bounds__(256) void prep_transpose4(
    const float* __restrict__ in, float* __restrict__ out, int R, int C,
    float s0, float s1, float s2, float s3) {
  int gid = blockIdx.x * 256 + threadIdx.x;
  int per = R * C;
  if (gid >= 4 * per) return;
  int e = gid / per;
  int rem = gid - e * per;
  int r = rem / C;
  int c = rem - r * C;
  float s = (e == 0) ? s0 : (e == 1) ? s1 : (e == 2) ? s2 : s3;
  out[(size_t)e * per + (size_t)c * R + r] = in[gid] * s;
}

// Combined residual+self weights, transposed:
// WcT[0] (track):    Wres[1]T + 0.5*(W2r[0]T + W2r[2]T)
// WcT[1] (playlist): Wres[0]T + W2r[1]T
// WcT[2] (artist):   Wres[2]T + W2r[3]T;  bc likewise from bres/b2.
__global__ __launch_bounds__(256) void prep_comb(
    const float* __restrict__ Wres, const float* __restrict__ W2r,
    const float* __restrict__ bres, const float* __restrict__ b2,
    float* __restrict__ WcT, float* __restrict__ bc) {
  int gid = blockIdx.x * 256 + threadIdx.x;
  const int per = DO * DH;
  if (gid < 3 * per) {
    int b = gid / per;
    int rem = gid - b * per;
    int k = rem / DO;
    int o = rem - k * DO;
    int resIdx = (b == 0) ? 1 : (b == 1) ? 0 : 2;
    float v = Wres[(size_t)resIdx * per + (size_t)o * DH + k];
    if (b == 0)
      v += 0.5f * (W2r[(size_t)0 * per + (size_t)o * DH + k] +
                   W2r[(size_t)2 * per + (size_t)o * DH + k]);
    else if (b == 1)
      v += W2r[(size_t)1 * per + (size_t)o * DH + k];
    else
      v += W2r[(size_t)3 * per + (size_t)o * DH + k];
    WcT[gid] = v;
  }
  if (gid < 3 * DO) {
    int b = gid / DO;
    int o = gid - b * DO;
    int resIdx = (b == 0) ? 1 : (b == 1) ? 0 : 2;
    float v = bres[resIdx * DO + o];
    if (b == 0)
      v += 0.5f * (b2[0 * DO + o] + b2[2 * DO + o]);
    else if (b == 1)
      v += b2[1 * DO + o];
    else
      v += b2[3 * DO + o];
    bc[gid] = v;
  }
}

// W1rcT = W1rT[0] + W1rT[2]  (each already scaled 0.5 by prep_transpose4)
__global__ __launch_bounds__(256) void prep_w1rc(const float* __restrict__ W1rT,
                                                 float* __restrict__ W1rcT) {
  int g = blockIdx.x * 256 + threadIdx.x;
  const int per = DIN * DH;
  if (g < per) W1rcT[g] = W1rT[g] + W1rT[2 * per + g];
}

// b1ct = 0.5*(b1[0] + b1[2])
__global__ __launch_bounds__(256) void prep_b1ct(const float* __restrict__ b1,
                                                 float* __restrict__ o) {
  int g = blockIdx.x * 256 + threadIdx.x;
  if (g < DH) o[g] = 0.5f * (b1[g] + b1[2 * DH + g]);
}

// ---------------- CSR build ----------------

__global__ __launch_bounds__(256) void hist_kernel(const int* __restrict__ dst,
                                                   int E, int* __restrict__ cnt) {
  int g = blockIdx.x * 256 + threadIdx.x;
  if (g < E) atomicAdd(&cnt[dst[g]], 1);
}

__global__ __launch_bounds__(256) void scan1(const int* __restrict__ cnt,
                                             int* __restrict__ part, int N) {
  __shared__ int s[256];
  int g = blockIdx.x * 256 + threadIdx.x;
  int t = threadIdx.x;
  s[t] = (g < N) ? cnt[g] : 0;
  __syncthreads();
  for (int o = 128; o > 0; o >>= 1) {
    if (t < o) s[t] += s[t + o];
    __syncthreads();
  }
  if (t == 0) part[blockIdx.x] = s[0];
}

__global__ __launch_bounds__(1024) void scan2(int* __restrict__ part, int nb) {
  __shared__ int s[1024];
  int t = threadIdx.x;
  int v = (t < nb) ? part[t] : 0;
  s[t] = v;
  __syncthreads();
  for (int o = 1; o < 1024; o <<= 1) {
    int x = (t >= o) ? s[t - o] : 0;
    __syncthreads();
    s[t] += x;
    __syncthreads();
  }
  if (t < nb) part[t] = s[t] - v;  // exclusive
}

__global__ __launch_bounds__(256) void scan3(const int* __restrict__ cnt,
                                             const int* __restrict__ part,
                                             int* __restrict__ rp,
                                             int* __restrict__ cursor, int N,
                                             int E) {
  __shared__ int s[256];
  int g = blockIdx.x * 256 + threadIdx.x;
  int t = threadIdx.x;
  int v = (g < N) ? cnt[g] : 0;
  s[t] = v;
  __syncthreads();
  for (int o = 1; o < 256; o <<= 1) {
    int x = (t >= o) ? s[t - o] : 0;
    __syncthreads();
    s[t] += x;
    __syncthreads();
  }
  if (g < N) {
    int excl = s[t] - v + part[blockIdx.x];
    rp[g] = excl;
    cursor[g] = excl;
    if (g == N - 1) rp[N] = E;
  }
}

__global__ __launch_bounds__(256) void fill_csr(const int* __restrict__ src,
                                                const int* __restrict__ dst,
                                                int E, int* __restrict__ cursor,
                                                int* __restrict__ col) {
  int g = blockIdx.x * 256 + threadIdx.x;
  if (g < E) {
    int p = atomicAdd(&cursor[dst[g]], 1);
    col[p] = src[g];
  }
}

// ---------------- gather (mean) ----------------
// out[g] (=|+=) mean_{j in adj(g)} (X[col[j]] (+ Xb[col[j]]))
template <int D4, bool XADD, bool ACCUM>
__global__ __launch_bounds__(256) void gather_mean(
    const float* __restrict__ X, const float* __restrict__ Xb,
    const int* __restrict__ rp, const int* __restrict__ col,
    float* __restrict__ out, int N) {
  constexpr int NG = 256 / D4;
  int g = blockIdx.x * NG + threadIdx.x / D4;
  int c = threadIdx.x % D4;
  if (g >= N) return;
  int s = rp[g], e = rp[g + 1];
  float4 acc = make_float4(0.f, 0.f, 0.f, 0.f);
  for (int j = s; j < e; ++j) {
    int sr = col[j];
    float4 v = reinterpret_cast<const float4*>(X)[(size_t)sr * D4 + c];
    if constexpr (XADD) {
      float4 w = reinterpret_cast<const float4*>(Xb)[(size_t)sr * D4 + c];
      v.x += w.x; v.y += w.y; v.z += w.z; v.w += w.w;
    }
    acc.x += v.x; acc.y += v.y; acc.z += v.z; acc.w += v.w;
  }
  float inv = 1.0f / fmaxf((float)(e - s), 1.0f);
  acc.x *= inv; acc.y *= inv; acc.z *= inv; acc.w *= inv;
  float4* op = reinterpret_cast<float4*>(out) + (size_t)g * D4 + c;
  if constexpr (ACCUM) {
    float4 o = *op;
    acc.x += o.x; acc.y += o.y; acc.z += o.z; acc.w += o.w;
  }
  *op = acc;
}

// ---------------- GEMM ----------------
// C[n] (=|+=) relu?( sum_a (A_a[n](+A1b[n] for a==1)) @ B_aT + bias + add0[n] )
// B_aT are [K][DOUT] row-major (pre-transposed/scaled on device).
template <int K, int DOUT, int NA, bool A1B, int NADD, bool ACC, bool HAS_BIAS,
          bool RELU>
__global__ __launch_bounds__(256) void gemm_kernel(
    const float* __restrict__ A0p, const float* __restrict__ A1p,
    const float* __restrict__ A1bp, const float* __restrict__ B0p,
    const float* __restrict__ B1p, const float* __restrict__ add0,
    const float* __restrict__ bias, float* __restrict__ C, int N) {
  constexpr int KC = 16;
  constexpr int ROWS = 64;
  constexpr int CT = DOUT / 4;
  constexpr int RG = 256 / CT;
  constexpr int RPT = ROWS / RG;

  __shared__ float As[NA][KC][ROWS];
  __shared__ float Bs[NA][KC][DOUT];

  const float* Ap[2] = {A0p, A1p};
  const float* Bp[2] = {B0p, B1p};

  const int tid = threadIdx.x;
  const int tc = tid % CT;
  const int tg = tid / CT;
  const int n0 = blockIdx.x * ROWS;

  float acc[RPT][4];
#pragma unroll
  for (int r = 0; r < RPT; ++r)
#pragma unroll
    for (int j = 0; j < 4; ++j) acc[r][j] = 0.f;

  for (int kc0 = 0; kc0 < K; kc0 += KC) {
    {
      int row = tid >> 2;
      int k4 = tid & 3;
      int n = n0 + row;
#pragma unroll
      for (int a = 0; a < NA; ++a) {
        float4 v = make_float4(0.f, 0.f, 0.f, 0.f);
        if (n < N) {
          v = reinterpret_cast<const float4*>(Ap[a] + (size_t)n * K + kc0)[k4];
          if constexpr (A1B) {
            if (a == 1) {
              float4 w =
                  reinterpret_cast<const float4*>(A1bp + (size_t)n * K + kc0)[k4];
              v.x += w.x; v.y += w.y; v.z += w.z; v.w += w.w;
            }
          }
        }
        As[a][k4 * 4 + 0][row] = v.x;
        As[a][k4 * 4 + 1][row] = v.y;
        As[a][k4 * 4 + 2][row] = v.z;
        As[a][k4 * 4 + 3][row] = v.w;
      }
    }
    {
      constexpr int TOT4 = KC * DOUT / 4;
#pragma unroll
      for (int i = tid; i < TOT4; i += 256) {
        int kk = i / (DOUT / 4);
        int c4 = i - kk * (DOUT / 4);
#pragma unroll
        for (int a = 0; a < NA; ++a)
          reinterpret_cast<float4*>(&Bs[a][kk][0])[c4] =
              reinterpret_cast<const float4*>(Bp[a] + (size_t)(kc0 + kk) * DOUT)[c4];
      }
    }
    __syncthreads();

#pragma unroll
    for (int k = 0; k < KC; ++k) {
#pragma unroll
      for (int a = 0; a < NA; ++a) {
        float4 bq = reinterpret_cast<const float4*>(&Bs[a][k][0])[tc];
#pragma unroll
        for (int rq = 0; rq < RPT / 4; ++rq) {
          float4 aq = *reinterpret_cast<const float4*>(&As[a][k][tg * RPT + rq * 4]);
#pragma unroll
          for (int i = 0; i < 4; ++i) {
            float av = (i == 0) ? aq.x : (i == 1) ? aq.y : (i == 2) ? aq.z : aq.w;
            int r = rq * 4 + i;
            acc[r][0] += av * bq.x;
            acc[r][1] += av * bq.y;
            acc[r][2] += av * bq.z;
            acc[r][3] += av * bq.w;
          }
        }
      }
    }
    __syncthreads();
  }

  float4 bq = make_float4(0.f, 0.f, 0.f, 0.f);
  if constexpr (HAS_BIAS) bq = reinterpret_cast<const float4*>(bias)[tc];
#pragma unroll
  for (int r = 0; r < RPT; ++r) {
    int n = n0 + tg * RPT + r;
    if (n < N) {
      float4 v = make_float4(acc[r][0] + bq.x, acc[r][1] + bq.y,
                             acc[r][2] + bq.z, acc[r][3] + bq.w);
      if constexpr (NADD >= 1) {
        float4 a0 = reinterpret_cast<const float4*>(add0)[(size_t)n * CT + tc];
        v.x += a0.x; v.y += a0.y; v.z += a0.z; v.w += a0.w;
      }
      float* cp = C + (size_t)n * DOUT + tc * 4;
      if constexpr (ACC) {
        float4 c0 = *reinterpret_cast<const float4*>(cp);
        v.x += c0.x; v.y += c0.y; v.z += c0.z; v.w += c0.w;
      }
      if constexpr (RELU) {
        v.x = fmaxf(v.x, 0.f); v.y = fmaxf(v.y, 0.f);
        v.z = fmaxf(v.z, 0.f); v.w = fmaxf(v.w, 0.f);
      }
      *reinterpret_cast<float4*>(cp) = v;
    }
  }
}

inline int cdiv(int a, int b) { return (a + b - 1) / b; }

}  // namespace

extern "C" void kernel_launch(void* const* d_in, const int* in_sizes, int n_in,
                              void* d_out, int out_size, void* d_ws,
                              size_t ws_size, hipStream_t stream) {
  const float* x_p   = (const float*)d_in[0];
  const float* x_t   = (const float*)d_in[1];
  const float* x_a   = (const float*)d_in[2];
  const float* emb_p = (const float*)d_in[3];
  const float* emb_a = (const float*)d_in[4];
  const float* W1l   = (const float*)d_in[5];
  const float* b1    = (const float*)d_in[6];
  const float* W1r   = (const float*)d_in[7];
  const float* W2l   = (const float*)d_in[8];
  const float* b2    = (const float*)d_in[9];
  const float* W2r   = (const float*)d_in[10];
  const float* Wres  = (const float*)d_in[11];
  const float* bres  = (const float*)d_in[12];
  const int* e_pt = (const int*)d_in[13];
  const int* e_tp = (const int*)d_in[14];
  const int* e_at = (const int*)d_in[15];
  const int* e_ta = (const int*)d_in[16];
  (void)in_sizes; (void)n_in; (void)out_size; (void)ws_size;

  float* out = (float*)d_out;
  float* p_out = out;
  float* t_out = out + (size_t)kNP * DO;
  float* a_out = out + (size_t)(kNP + kNT) * DO;

  float* ws = (float*)d_ws;
  size_t off = 0;
  auto alloc = [&](size_t nf) { float* p = ws + off; off += nf; return p; };

  float* t1     = alloc((size_t)kNT * DH);   // 51.2M
  float* p1     = alloc((size_t)kNP * DH);   // 12.8M
  float* a1     = alloc((size_t)kNA * DH);   // 5.12M
  float* agg    = alloc((size_t)kNT * DIN);  // 25.6M shared, sequential reuse
  float* agg_tp = alloc((size_t)kNP * DIN);  // 6.4M (later y_p)
  float* agg_ta = alloc((size_t)kNA * DIN);  // 2.56M (later y_a)
  const int per1 = DIN * DH;  // 32768
  const int per2 = DH * DO;   // 32768
  float* W1lT  = alloc(4 * per1);
  float* W1rT  = alloc(4 * per1);
  float* W1rcT = alloc(per1);
  float* W2lT  = alloc(4 * per2);
  float* WcT   = alloc(3 * per2);
  float* bc    = alloc(3 * DO);
  float* b1ct  = alloc(DH);

  // int region
  int* iws = (int*)(ws + off);
  size_t ioff = 0;
  auto ialloc = [&](size_t ni) { int* p = iws + ioff; ioff += (ni + 3) & ~size_t(3); return p; };
  int* rp_pt = ialloc(kNT + 1);
  int* rp_tp = ialloc(kNP + 1);
  int* rp_at = ialloc(kNT + 1);
  int* rp_ta = ialloc(kNA + 1);
  int* cur_pt = ialloc(kNT);  // doubles as cnt
  int* cur_tp = ialloc(kNP);
  int* cur_at = ialloc(kNT);
  int* cur_ta = ialloc(kNA);
  int* col_pt = ialloc(kEPT);
  int* col_tp = ialloc(kETP);
  int* col_at = ialloc(kEAT);
  int* col_ta = ialloc(kETA);
  int* part = ialloc(1024);

  // ---- 1. weight prep ----
  prep_transpose4<<<cdiv(4 * per1, 256), 256, 0, stream>>>(W1l, W1lT, DH, DIN, 0.5f, 1.f, 0.5f, 1.f);
  prep_transpose4<<<cdiv(4 * per1, 256), 256, 0, stream>>>(W1r, W1rT, DH, DIN, 0.5f, 1.f, 0.5f, 1.f);
  prep_transpose4<<<cdiv(4 * per2, 256), 256, 0, stream>>>(W2l, W2lT, DO, DH, 0.5f, 1.f, 0.5f, 1.f);
  prep_comb<<<cdiv(3 * per2, 256), 256, 0, stream>>>(Wres, W2r, bres, b2, WcT, bc);
  prep_w1rc<<<cdiv(per1, 256), 256, 0, stream>>>(W1rT, W1rcT);
  prep_b1ct<<<1, 256, 0, stream>>>(b1, b1ct);

  // ---- 2. CSR build x4 ----
  hipMemsetAsync(cur_pt, 0, (size_t)(2 * kNT + kNP + kNA) * sizeof(int), stream);
  struct CsrDesc { const int* edge; int E; int N; int* rp; int* cur; int* col; };
  CsrDesc descs[4] = {
      {e_pt, kEPT, kNT, rp_pt, cur_pt, col_pt},
      {e_tp, kETP, kNP, rp_tp, cur_tp, col_tp},
      {e_at, kEAT, kNT, rp_at, cur_at, col_at},
      {e_ta, kETA, kNA, rp_ta, cur_ta, col_ta},
  };
  for (auto& d : descs)
    hist_kernel<<<cdiv(d.E, 256), 256, 0, stream>>>(d.edge + d.E, d.E, d.cur);
  for (auto& d : descs) {
    int nb = cdiv(d.N, 256);
    scan1<<<nb, 256, 0, stream>>>(d.cur, part, d.N);
    scan2<<<1, 1024, 0, stream>>>(part, nb);
    scan3<<<nb, 256, 0, stream>>>(d.cur, part, d.rp, d.cur, d.N, d.E);
    fill_csr<<<cdiv(d.E, 256), 256, 0, stream>>>(d.edge, d.edge + d.E, d.E, d.cur, d.col);
  }

  // ---- 3. conv1: track (2-pass over shared agg) ----
  gather_mean<32, true, false><<<cdiv(kNT, 8), 256, 0, stream>>>(
      x_p, emb_p, rp_pt, col_pt, agg, kNT);
  gemm_kernel<DIN, DH, 2, false, 0, false, true, false>
      <<<cdiv(kNT, 64), 256, 0, stream>>>(agg, x_t, nullptr, W1lT + 0 * per1,
                                          W1rcT, nullptr, b1ct, t1, kNT);
  gather_mean<32, true, false><<<cdiv(kNT, 8), 256, 0, stream>>>(
      x_a, emb_a, rp_at, col_at, agg, kNT);
  gemm_kernel<DIN, DH, 1, false, 0, true, false, true>
      <<<cdiv(kNT, 64), 256, 0, stream>>>(agg, nullptr, nullptr,
                                          W1lT + 2 * per1, nullptr, nullptr,
                                          nullptr, t1, kNT);

  // ---- 4. conv1: playlist / artist ----
  gather_mean<32, false, false><<<cdiv(kNP, 8), 256, 0, stream>>>(
      x_t, nullptr, rp_tp, col_tp, agg_tp, kNP);
  gemm_kernel<DIN, DH, 2, true, 0, false, true, true>
      <<<cdiv(kNP, 64), 256, 0, stream>>>(agg_tp, x_p, emb_p, W1lT + 1 * per1,
                                          W1rT + 1 * per1, nullptr, b1 + 1 * DH,
                                          p1, kNP);
  gather_mean<32, false, false><<<cdiv(kNA, 8), 256, 0, stream>>>(
      x_t, nullptr, rp_ta, col_ta, agg_ta, kNA);
  gemm_kernel<DIN, DH, 2, true, 0, false, true, true>
      <<<cdiv(kNA, 64), 256, 0, stream>>>(agg_ta, x_a, emb_a, W1lT + 3 * per1,
                                          W1rT + 3 * per1, nullptr, b1 + 3 * DH,
                                          a1, kNA);

  // ---- 5. conv2 down-projections (transform before aggregate) ----
  float* y_p = agg_tp;  // 50k x 128
  float* y_a = agg_ta;  // 20k x 128
  gemm_kernel<DH, DO, 1, false, 0, false, false, false>
      <<<cdiv(kNP, 64), 256, 0, stream>>>(p1, nullptr, nullptr, W2lT + 0 * per2,
                                          nullptr, nullptr, nullptr, y_p, kNP);
  gemm_kernel<DH, DO, 1, false, 0, false, false, false>
      <<<cdiv(kNA, 64), 256, 0, stream>>>(a1, nullptr, nullptr, W2lT + 2 * per2,
                                          nullptr, nullptr, nullptr, y_a, kNA);

  // ---- 6. t_out: pass1 (t1@WcT0 + g_pt + bc0), pass2 (+= g_at) ----
  float* g_pt = agg;
  gather_mean<32, false, false><<<cdiv(kNT, 8), 256, 0, stream>>>(
      y_p, nullptr, rp_pt, col_pt, g_pt, kNT);
  gemm_kernel<DH, DO, 1, false, 1, false, true, false>
      <<<cdiv(kNT, 64), 256, 0, stream>>>(t1, nullptr, nullptr, WcT + 0 * per2,
                                          nullptr, g_pt, bc + 0 * DO, t_out,
                                          kNT);
  gather_mean<32, false, true><<<cdiv(kNT, 8), 256, 0, stream>>>(
      y_a, nullptr, rp_at, col_at, t_out, kNT);

  // ---- 7. tp/ta 256-d gathers of t1 (agg free again) ----
  float* gtp = agg;                        // 50k x 256 = 12.8M
  float* gta = agg + (size_t)kNP * DH;     // 20k x 256 = 5.12M (fits in 25.6M)
  gather_mean<64, false, false><<<cdiv(kNP, 4), 256, 0, stream>>>(
      t1, nullptr, rp_tp, col_tp, gtp, kNP);
  gather_mean<64, false, false><<<cdiv(kNA, 4), 256, 0, stream>>>(
      t1, nullptr, rp_ta, col_ta, gta, kNA);

  // ---- 8. p_out / a_out ----
  gemm_kernel<DH, DO, 2, false, 0, false, true, false>
      <<<cdiv(kNP, 64), 256, 0, stream>>>(gtp, p1, nullptr, W2lT + 1 * per2,
                                          WcT + 1 * per2, nullptr, bc + 1 * DO,
                                          p_out, kNP);
  gemm_kernel<DH, DO, 2, false, 0, false, true, false>
      <<<cdiv(kNA, 64), 256, 0, stream>>>(gta, a1, nullptr, W2lT + 3 * per2,
                                          WcT + 2 * per2, nullptr, bc + 2 * DO,
                                          a_out, kNA);
}

// Round 4
// 1107.115 us; speedup vs baseline: 14.4387x; 2.0464x over previous
//
#include <hip/hip_runtime.h>

namespace {

typedef __attribute__((ext_vector_type(8))) short short8;
typedef __attribute__((ext_vector_type(4))) float f32x4;

constexpr int kNP = 50000, kNT = 200000, kNA = 20000;
constexpr int kEPT = 1000000, kETP = 1000000, kEAT = 400000, kETA = 400000;
constexpr int DIN = 128, DH = 256, DO = 128;

__device__ __forceinline__ float bf2f(short u) {
  union { unsigned int i; float f; } c;
  c.i = ((unsigned int)(unsigned short)u) << 16;
  return c.f;
}
__device__ __forceinline__ short f2bf(float f) {
  union { float f; unsigned int i; } c;
  c.f = f;
  unsigned int r = c.i + 0x7fffu + ((c.i >> 16) & 1u);  // RNE
  return (short)(r >> 16);
}

// ---------------- converts ----------------

template <bool ADD>
__global__ __launch_bounds__(256) void cvt_bf16(const float* __restrict__ a,
                                                const float* __restrict__ b,
                                                short* __restrict__ o, int n8) {
  int g = blockIdx.x * 256 + threadIdx.x;
  if (g >= n8) return;
  const float4* a4 = reinterpret_cast<const float4*>(a);
  float4 x0 = a4[2 * g], x1 = a4[2 * g + 1];
  if constexpr (ADD) {
    const float4* b4 = reinterpret_cast<const float4*>(b);
    float4 y0 = b4[2 * g], y1 = b4[2 * g + 1];
    x0.x += y0.x; x0.y += y0.y; x0.z += y0.z; x0.w += y0.w;
    x1.x += y1.x; x1.y += y1.y; x1.z += y1.z; x1.w += y1.w;
  }
  short8 w;
  w[0] = f2bf(x0.x); w[1] = f2bf(x0.y); w[2] = f2bf(x0.z); w[3] = f2bf(x0.w);
  w[4] = f2bf(x1.x); w[5] = f2bf(x1.y); w[6] = f2bf(x1.z); w[7] = f2bf(x1.w);
  reinterpret_cast<short8*>(o)[g] = w;
}

// ---------------- weight prep (bf16, native [out][in] layout) ----------------

__global__ __launch_bounds__(256) void scale4_bf16(const float* __restrict__ in,
                                                   short* __restrict__ out,
                                                   int per, float s0, float s1,
                                                   float s2, float s3) {
  int g = blockIdx.x * 256 + threadIdx.x;
  if (g >= 4 * per) return;
  int e = g / per;
  float s = (e == 0) ? s0 : (e == 1) ? s1 : (e == 2) ? s2 : s3;
  out[g] = f2bf(in[g] * s);
}

__global__ __launch_bounds__(256) void wsum2_bf16(const float* __restrict__ in1,
                                                  const float* __restrict__ in2,
                                                  short* __restrict__ out, int n,
                                                  float sa, float sb) {
  int g = blockIdx.x * 256 + threadIdx.x;
  if (g < n) out[g] = f2bf(sa * in1[g] + sb * in2[g]);
}

// Wc[0] (track):    Wres[1] + 0.5*(W2r[0]+W2r[2])
// Wc[1] (playlist): Wres[0] + W2r[1]
// Wc[2] (artist):   Wres[2] + W2r[3];  bc likewise from bres/b2 (fp32).
__global__ __launch_bounds__(256) void prep_wc(const float* __restrict__ Wres,
                                               const float* __restrict__ W2r,
                                               const float* __restrict__ bres,
                                               const float* __restrict__ b2,
                                               short* __restrict__ Wc,
                                               float* __restrict__ bc) {
  int gid = blockIdx.x * 256 + threadIdx.x;
  const int per = DO * DH;
  if (gid < 3 * per) {
    int b = gid / per;
    int idx = gid - b * per;
    int resIdx = (b == 0) ? 1 : (b == 1) ? 0 : 2;
    float v = Wres[(size_t)resIdx * per + idx];
    if (b == 0)
      v += 0.5f * (W2r[(size_t)0 * per + idx] + W2r[(size_t)2 * per + idx]);
    else if (b == 1)
      v += W2r[(size_t)1 * per + idx];
    else
      v += W2r[(size_t)3 * per + idx];
    Wc[gid] = f2bf(v);
  }
  if (gid < 3 * DO) {
    int b = gid / DO;
    int o = gid - b * DO;
    int resIdx = (b == 0) ? 1 : (b == 1) ? 0 : 2;
    float v = bres[resIdx * DO + o];
    if (b == 0)
      v += 0.5f * (b2[0 * DO + o] + b2[2 * DO + o]);
    else if (b == 1)
      v += b2[1 * DO + o];
    else
      v += b2[3 * DO + o];
    bc[gid] = v;
  }
}

__global__ __launch_bounds__(256) void prep_b1ct(const float* __restrict__ b1,
                                                 float* __restrict__ o) {
  int g = blockIdx.x * 256 + threadIdx.x;
  if (g < DH) o[g] = 0.5f * (b1[g] + b1[2 * DH + g]);
}

// ---------------- CSR build ----------------

__global__ __launch_bounds__(256) void hist_kernel(const int* __restrict__ dst,
                                                   int E, int* __restrict__ cnt) {
  int g = blockIdx.x * 256 + threadIdx.x;
  if (g < E) atomicAdd(&cnt[dst[g]], 1);
}

__global__ __launch_bounds__(256) void scan1(const int* __restrict__ cnt,
                                             int* __restrict__ part, int N) {
  __shared__ int s[256];
  int g = blockIdx.x * 256 + threadIdx.x;
  int t = threadIdx.x;
  s[t] = (g < N) ? cnt[g] : 0;
  __syncthreads();
  for (int o = 128; o > 0; o >>= 1) {
    if (t < o) s[t] += s[t + o];
    __syncthreads();
  }
  if (t == 0) part[blockIdx.x] = s[0];
}

__global__ __launch_bounds__(1024) void scan2(int* __restrict__ part, int nb) {
  __shared__ int s[1024];
  int t = threadIdx.x;
  int v = (t < nb) ? part[t] : 0;
  s[t] = v;
  __syncthreads();
  for (int o = 1; o < 1024; o <<= 1) {
    int x = (t >= o) ? s[t - o] : 0;
    __syncthreads();
    s[t] += x;
    __syncthreads();
  }
  if (t < nb) part[t] = s[t] - v;  // exclusive
}

__global__ __launch_bounds__(256) void scan3(const int* __restrict__ cnt,
                                             const int* __restrict__ part,
                                             int* __restrict__ rp,
                                             int* __restrict__ cursor, int N,
                                             int E) {
  __shared__ int s[256];
  int g = blockIdx.x * 256 + threadIdx.x;
  int t = threadIdx.x;
  int v = (g < N) ? cnt[g] : 0;
  s[t] = v;
  __syncthreads();
  for (int o = 1; o < 256; o <<= 1) {
    int x = (t >= o) ? s[t - o] : 0;
    __syncthreads();
    s[t] += x;
    __syncthreads();
  }
  if (g < N) {
    int excl = s[t] - v + part[blockIdx.x];
    rp[g] = excl;
    cursor[g] = excl;
    if (g == N - 1) rp[N] = E;
  }
}

__global__ __launch_bounds__(256) void fill_csr(const int* __restrict__ src,
                                                const int* __restrict__ dst,
                                                int E, int* __restrict__ cursor,
                                                int* __restrict__ col) {
  int g = blockIdx.x * 256 + threadIdx.x;
  if (g < E) {
    int p = atomicAdd(&cursor[dst[g]], 1);
    col[p] = src[g];
  }
}

// ---------------- gathers (bf16 in, fp32 accumulate) ----------------
// MODE 0: write bf16; 1: write f32; 2: f32 accumulate (+=)
template <int D8, int MODE>
__global__ __launch_bounds__(256) void gather_b(const short* __restrict__ X,
                                                const int* __restrict__ rp,
                                                const int* __restrict__ col,
                                                void* __restrict__ out, int N) {
  constexpr int NG = 256 / D8;
  int g = blockIdx.x * NG + (int)threadIdx.x / D8;
  int c = (int)threadIdx.x % D8;
  if (g >= N) return;
  int s = rp[g], e = rp[g + 1];
  float acc[8] = {0.f, 0.f, 0.f, 0.f, 0.f, 0.f, 0.f, 0.f};
  const short8* Xv = reinterpret_cast<const short8*>(X);
  for (int j = s; j < e; ++j) {
    short8 v = Xv[(size_t)col[j] * D8 + c];
#pragma unroll
    for (int i = 0; i < 8; ++i) acc[i] += bf2f(v[i]);
  }
  float inv = 1.0f / fmaxf((float)(e - s), 1.0f);
#pragma unroll
  for (int i = 0; i < 8; ++i) acc[i] *= inv;
  if constexpr (MODE == 0) {
    short8 w;
#pragma unroll
    for (int i = 0; i < 8; ++i) w[i] = f2bf(acc[i]);
    reinterpret_cast<short8*>(out)[(size_t)g * D8 + c] = w;
  } else {
    float* po = reinterpret_cast<float*>(out) + ((size_t)g * D8 + c) * 8;
    float4 lo = make_float4(acc[0], acc[1], acc[2], acc[3]);
    float4 hi = make_float4(acc[4], acc[5], acc[6], acc[7]);
    if constexpr (MODE == 2) {
      float4 o0 = reinterpret_cast<const float4*>(po)[0];
      float4 o1 = reinterpret_cast<const float4*>(po)[1];
      lo.x += o0.x; lo.y += o0.y; lo.z += o0.z; lo.w += o0.w;
      hi.x += o1.x; hi.y += o1.y; hi.z += o1.z; hi.w += o1.w;
    }
    reinterpret_cast<float4*>(po)[0] = lo;
    reinterpret_cast<float4*>(po)[1] = hi;
  }
}

// out[g] += mean1(X1 over csr1) + mean2(X2 over csr2)   (fp32 out)
template <int D8>
__global__ __launch_bounds__(256) void gather2_acc(
    const short* __restrict__ X1, const int* __restrict__ rp1,
    const int* __restrict__ col1, const short* __restrict__ X2,
    const int* __restrict__ rp2, const int* __restrict__ col2,
    float* __restrict__ out, int N) {
  constexpr int NG = 256 / D8;
  int g = blockIdx.x * NG + (int)threadIdx.x / D8;
  int c = (int)threadIdx.x % D8;
  if (g >= N) return;
  float tot[8] = {0.f, 0.f, 0.f, 0.f, 0.f, 0.f, 0.f, 0.f};
  {
    int s = rp1[g], e = rp1[g + 1];
    float a[8] = {0.f, 0.f, 0.f, 0.f, 0.f, 0.f, 0.f, 0.f};
    const short8* Xv = reinterpret_cast<const short8*>(X1);
    for (int j = s; j < e; ++j) {
      short8 v = Xv[(size_t)col1[j] * D8 + c];
#pragma unroll
      for (int i = 0; i < 8; ++i) a[i] += bf2f(v[i]);
    }
    float inv = 1.0f / fmaxf((float)(e - s), 1.0f);
#pragma unroll
    for (int i = 0; i < 8; ++i) tot[i] += a[i] * inv;
  }
  {
    int s = rp2[g], e = rp2[g + 1];
    float a[8] = {0.f, 0.f, 0.f, 0.f, 0.f, 0.f, 0.f, 0.f};
    const short8* Xv = reinterpret_cast<const short8*>(X2);
    for (int j = s; j < e; ++j) {
      short8 v = Xv[(size_t)col2[j] * D8 + c];
#pragma unroll
      for (int i = 0; i < 8; ++i) a[i] += bf2f(v[i]);
    }
    float inv = 1.0f / fmaxf((float)(e - s), 1.0f);
#pragma unroll
    for (int i = 0; i < 8; ++i) tot[i] += a[i] * inv;
  }
  float* po = out + ((size_t)g * D8 + c) * 8;
  float4 o0 = reinterpret_cast<const float4*>(po)[0];
  float4 o1 = reinterpret_cast<const float4*>(po)[1];
  o0.x += tot[0]; o0.y += tot[1]; o0.z += tot[2]; o0.w += tot[3];
  o1.x += tot[4]; o1.y += tot[5]; o1.z += tot[6]; o1.w += tot[7];
  reinterpret_cast<float4*>(po)[0] = o0;
  reinterpret_cast<float4*>(po)[1] = o1;
}

// ---------------- MFMA GEMM ----------------
// C[n][o] = relu?( sum_a A_a[n][:] . B_a[o][:] + bias[o] )
// A_a: [N][K] bf16 row-major; B_a: [DOUT][K] bf16 row-major (native weight layout).
// Output: bf16 (Cb) or fp32 (Cf).
template <int K, int DOUT, int NA, bool BF16OUT, bool BIAS, bool RELU>
__global__ __launch_bounds__(256) void mfma_gemm(
    const short* __restrict__ A0, const short* __restrict__ A1,
    const short* __restrict__ A2, const short* __restrict__ B0,
    const short* __restrict__ B1, const short* __restrict__ B2,
    const float* __restrict__ bias, float* __restrict__ Cf,
    short* __restrict__ Cb, int N) {
  constexpr int CTPW = DOUT / 64;  // col tiles per wave (4 for 256, 2 for 128)
  constexpr int K8 = K / 8;

  __shared__ short As[64][K + 8];     // +8 pad: row stride = 4 banks mod 32
  __shared__ short Bs[DOUT][40];      // 32-k chunk, +8 pad

  const int tid = threadIdx.x;
  const int lane = tid & 63;
  const int w = tid >> 6;
  const int lr = lane & 15;   // row (A) / col (B) within 16-tile
  const int ls = lane >> 4;   // k-segment (8 bf16 each)
  const int n0 = blockIdx.x * 64;

  const short* Ap[3] = {A0, A1, A2};
  const short* Bp[3] = {B0, B1, B2};

  f32x4 acc[4][CTPW] = {};

#pragma unroll
  for (int a = 0; a < NA; ++a) {
    // stage A_a (full K): 64 x K bf16
#pragma unroll
    for (int it = 0; it < K / 32; ++it) {
      int idx = it * 256 + tid;
      int row = idx / K8;
      int c8 = idx - row * K8;
      short8 v = {0, 0, 0, 0, 0, 0, 0, 0};
      int n = n0 + row;
      if (n < N)
        v = *reinterpret_cast<const short8*>(Ap[a] + (size_t)n * K + c8 * 8);
      *reinterpret_cast<short8*>(&As[row][c8 * 8]) = v;
    }
    for (int kk = 0; kk < K / 32; ++kk) {
      // stage B_a chunk [DOUT][32]
#pragma unroll
      for (int it = 0; it < DOUT / 64; ++it) {
        int idx = it * 256 + tid;
        int o = idx >> 2;
        int c8 = idx & 3;
        short8 v = *reinterpret_cast<const short8*>(Bp[a] + (size_t)o * K +
                                                    kk * 32 + c8 * 8);
        *reinterpret_cast<short8*>(&Bs[o][c8 * 8]) = v;
      }
      __syncthreads();
      short8 bf[CTPW];
#pragma unroll
      for (int tn = 0; tn < CTPW; ++tn)
        bf[tn] = *reinterpret_cast<const short8*>(
            &Bs[w * CTPW * 16 + tn * 16 + lr][ls * 8]);
#pragma unroll
      for (int tm = 0; tm < 4; ++tm) {
        short8 af = *reinterpret_cast<const short8*>(
            &As[tm * 16 + lr][kk * 32 + ls * 8]);
#pragma unroll
        for (int tn = 0; tn < CTPW; ++tn)
          acc[tm][tn] = __builtin_amdgcn_mfma_f32_16x16x32_bf16(
              af, bf[tn], acc[tm][tn], 0, 0, 0);
      }
      __syncthreads();
    }
  }

  // epilogue: C row = tm*16 + ls*4 + r, col = w*CTPW*16 + tn*16 + lr
#pragma unroll
  for (int tm = 0; tm < 4; ++tm) {
#pragma unroll
    for (int tn = 0; tn < CTPW; ++tn) {
      int colg = w * CTPW * 16 + tn * 16 + lr;
      float bv = 0.f;
      if constexpr (BIAS) bv = bias[colg];
#pragma unroll
      for (int r = 0; r < 4; ++r) {
        int n = n0 + tm * 16 + ls * 4 + r;
        if (n < N) {
          float v = acc[tm][tn][r] + bv;
          if constexpr (RELU) v = fmaxf(v, 0.f);
          if constexpr (BF16OUT)
            Cb[(size_t)n * DOUT + colg] = f2bf(v);
          else
            Cf[(size_t)n * DOUT + colg] = v;
        }
      }
    }
  }
}

inline int cdiv(int a, int b) { return (a + b - 1) / b; }

}  // namespace

extern "C" void kernel_launch(void* const* d_in, const int* in_sizes, int n_in,
                              void* d_out, int out_size, void* d_ws,
                              size_t ws_size, hipStream_t stream) {
  const float* x_p   = (const float*)d_in[0];
  const float* x_t   = (const float*)d_in[1];
  const float* x_a   = (const float*)d_in[2];
  const float* emb_p = (const float*)d_in[3];
  const float* emb_a = (const float*)d_in[4];
  const float* W1l   = (const float*)d_in[5];
  const float* b1    = (const float*)d_in[6];
  const float* W1r   = (const float*)d_in[7];
  const float* W2l   = (const float*)d_in[8];
  const float* b2    = (const float*)d_in[9];
  const float* W2r   = (const float*)d_in[10];
  const float* Wres  = (const float*)d_in[11];
  const float* bres  = (const float*)d_in[12];
  const int* e_pt = (const int*)d_in[13];
  const int* e_tp = (const int*)d_in[14];
  const int* e_at = (const int*)d_in[15];
  const int* e_ta = (const int*)d_in[16];
  (void)in_sizes; (void)n_in; (void)out_size; (void)ws_size;

  float* out = (float*)d_out;
  float* p_out = out;
  float* t_out = out + (size_t)kNP * DO;
  float* a_out = out + (size_t)(kNP + kNT) * DO;

  char* base = (char*)d_ws;
  size_t off = 0;
  auto alloc = [&](size_t bytes) {
    off = (off + 255) & ~size_t(255);
    void* p = base + off;
    off += bytes;
    return p;
  };

  const int per1 = DIN * DH;  // 32768
  const int per2 = DH * DO;   // 32768

  short* t1b   = (short*)alloc((size_t)kNT * DH * 2);
  short* p1b   = (short*)alloc((size_t)kNP * DH * 2);
  short* a1b   = (short*)alloc((size_t)kNA * DH * 2);
  short* aggpt = (short*)alloc((size_t)kNT * DIN * 2);
  short* aggat = (short*)alloc((size_t)kNT * DIN * 2);
  short* aggtp = (short*)alloc((size_t)kNP * DIN * 2);
  short* aggta = (short*)alloc((size_t)kNA * DIN * 2);
  short* xpeb  = (short*)alloc((size_t)kNP * DIN * 2);
  short* xaeb  = (short*)alloc((size_t)kNA * DIN * 2);
  short* xtb   = (short*)alloc((size_t)kNT * DIN * 2);
  short* ypb   = (short*)alloc((size_t)kNP * DO * 2);
  short* yab   = (short*)alloc((size_t)kNA * DO * 2);
  short* gtpb  = (short*)alloc((size_t)kNP * DH * 2);
  short* gtab  = (short*)alloc((size_t)kNA * DH * 2);
  short* w1lb  = (short*)alloc(4 * per1 * 2);
  short* w1rb  = (short*)alloc(4 * per1 * 2);
  short* w1rcb = (short*)alloc(per1 * 2);
  short* w2lb  = (short*)alloc(4 * per2 * 2);
  short* wcb   = (short*)alloc(3 * per2 * 2);
  float* bc    = (float*)alloc(3 * DO * 4);
  float* b1ct  = (float*)alloc(DH * 4);

  int* rp_pt  = (int*)alloc((kNT + 1) * 4);
  int* rp_tp  = (int*)alloc((kNP + 1) * 4);
  int* rp_at  = (int*)alloc((kNT + 1) * 4);
  int* rp_ta  = (int*)alloc((kNA + 1) * 4);
  int* cur_pt = (int*)alloc(kNT * 4);
  int* cur_tp = (int*)alloc(kNP * 4);
  int* cur_at = (int*)alloc(kNT * 4);
  int* cur_ta = (int*)alloc(kNA * 4);
  int* col_pt = (int*)alloc(kEPT * 4);
  int* col_tp = (int*)alloc(kETP * 4);
  int* col_at = (int*)alloc(kEAT * 4);
  int* col_ta = (int*)alloc(kETA * 4);
  int* part   = (int*)alloc(1024 * 4);

  // ---- 0. bf16 converts of dense inputs ----
  cvt_bf16<true><<<cdiv(kNP * DIN / 8, 256), 256, 0, stream>>>(x_p, emb_p, xpeb, kNP * DIN / 8);
  cvt_bf16<true><<<cdiv(kNA * DIN / 8, 256), 256, 0, stream>>>(x_a, emb_a, xaeb, kNA * DIN / 8);
  cvt_bf16<false><<<cdiv(kNT * DIN / 8, 256), 256, 0, stream>>>(x_t, nullptr, xtb, kNT * DIN / 8);

  // ---- 1. weight prep (bf16, native [out][in]) ----
  scale4_bf16<<<cdiv(4 * per1, 256), 256, 0, stream>>>(W1l, w1lb, per1, 0.5f, 1.f, 0.5f, 1.f);
  scale4_bf16<<<cdiv(4 * per1, 256), 256, 0, stream>>>(W1r, w1rb, per1, 1.f, 1.f, 1.f, 1.f);
  wsum2_bf16<<<cdiv(per1, 256), 256, 0, stream>>>(W1r, W1r + 2 * per1, w1rcb, per1, 0.5f, 0.5f);
  scale4_bf16<<<cdiv(4 * per2, 256), 256, 0, stream>>>(W2l, w2lb, per2, 0.5f, 1.f, 0.5f, 1.f);
  prep_wc<<<cdiv(3 * per2, 256), 256, 0, stream>>>(Wres, W2r, bres, b2, wcb, bc);
  prep_b1ct<<<1, 256, 0, stream>>>(b1, b1ct);

  // ---- 2. CSR build x4 ----
  hipMemsetAsync(cur_pt, 0, (size_t)kNT * 4, stream);
  hipMemsetAsync(cur_tp, 0, (size_t)kNP * 4, stream);
  hipMemsetAsync(cur_at, 0, (size_t)kNT * 4, stream);
  hipMemsetAsync(cur_ta, 0, (size_t)kNA * 4, stream);
  struct CsrDesc { const int* edge; int E; int N; int* rp; int* cur; int* col; };
  CsrDesc descs[4] = {
      {e_pt, kEPT, kNT, rp_pt, cur_pt, col_pt},
      {e_tp, kETP, kNP, rp_tp, cur_tp, col_tp},
      {e_at, kEAT, kNT, rp_at, cur_at, col_at},
      {e_ta, kETA, kNA, rp_ta, cur_ta, col_ta},
  };
  for (auto& d : descs)
    hist_kernel<<<cdiv(d.E, 256), 256, 0, stream>>>(d.edge + d.E, d.E, d.cur);
  for (auto& d : descs) {
    int nb = cdiv(d.N, 256);
    scan1<<<nb, 256, 0, stream>>>(d.cur, part, d.N);
    scan2<<<1, 1024, 0, stream>>>(part, nb);
    scan3<<<nb, 256, 0, stream>>>(d.cur, part, d.rp, d.cur, d.N, d.E);
    fill_csr<<<cdiv(d.E, 256), 256, 0, stream>>>(d.edge, d.edge + d.E, d.E, d.cur, d.col);
  }

  // ---- 3. conv1 gathers (bf16 means) ----
  gather_b<16, 0><<<cdiv(kNT, 16), 256, 0, stream>>>(xpeb, rp_pt, col_pt, aggpt, kNT);
  gather_b<16, 0><<<cdiv(kNT, 16), 256, 0, stream>>>(xaeb, rp_at, col_at, aggat, kNT);
  gather_b<16, 0><<<cdiv(kNP, 16), 256, 0, stream>>>(xtb, rp_tp, col_tp, aggtp, kNP);
  gather_b<16, 0><<<cdiv(kNA, 16), 256, 0, stream>>>(xtb, rp_ta, col_ta, aggta, kNA);

  // ---- 4. conv1 GEMMs (MFMA) ----
  mfma_gemm<DIN, DH, 3, true, true, true><<<cdiv(kNT, 64), 256, 0, stream>>>(
      aggpt, aggat, xtb, w1lb, w1lb + 2 * per1, w1rcb, b1ct, nullptr, t1b, kNT);
  mfma_gemm<DIN, DH, 2, true, true, true><<<cdiv(kNP, 64), 256, 0, stream>>>(
      aggtp, xpeb, nullptr, w1lb + 1 * per1, w1rb + 1 * per1, nullptr,
      b1 + 1 * DH, nullptr, p1b, kNP);
  mfma_gemm<DIN, DH, 2, true, true, true><<<cdiv(kNA, 64), 256, 0, stream>>>(
      aggta, xaeb, nullptr, w1lb + 3 * per1, w1rb + 3 * per1, nullptr,
      b1 + 3 * DH, nullptr, a1b, kNA);

  // ---- 5. conv2 down-projections (transform before aggregate) ----
  mfma_gemm<DH, DO, 1, true, false, false><<<cdiv(kNP, 64), 256, 0, stream>>>(
      p1b, nullptr, nullptr, w2lb, nullptr, nullptr, nullptr, nullptr, ypb, kNP);
  mfma_gemm<DH, DO, 1, true, false, false><<<cdiv(kNA, 64), 256, 0, stream>>>(
      a1b, nullptr, nullptr, w2lb + 2 * per2, nullptr, nullptr, nullptr,
      nullptr, yab, kNA);

  // ---- 6. t_out = t1 @ Wc0 + bc0, then += mean_pt(y_p) + mean_at(y_a) ----
  mfma_gemm<DH, DO, 1, false, true, false><<<cdiv(kNT, 64), 256, 0, stream>>>(
      t1b, nullptr, nullptr, wcb, nullptr, nullptr, bc, t_out, nullptr, kNT);
  gather2_acc<16><<<cdiv(kNT, 16), 256, 0, stream>>>(
      ypb, rp_pt, col_pt, yab, rp_at, col_at, t_out, kNT);

  // ---- 7. 256-d gathers of t1 ----
  gather_b<32, 0><<<cdiv(kNP, 8), 256, 0, stream>>>(t1b, rp_tp, col_tp, gtpb, kNP);
  gather_b<32, 0><<<cdiv(kNA, 8), 256, 0, stream>>>(t1b, rp_ta, col_ta, gtab, kNA);

  // ---- 8. p_out / a_out ----
  mfma_gemm<DH, DO, 2, false, true, false><<<cdiv(kNP, 64), 256, 0, stream>>>(
      gtpb, p1b, nullptr, w2lb + 1 * per2, wcb + 1 * per2, nullptr, bc + DO,
      p_out, nullptr, kNP);
  mfma_gemm<DH, DO, 2, false, true, false><<<cdiv(kNA, 64), 256, 0, stream>>>(
      gtab, a1b, nullptr, w2lb + 3 * per2, wcb + 2 * per2, nullptr, bc + 2 * DO,
      a_out, nullptr, kNA);
}